// Round 1
// baseline (709.570 us; speedup 1.0000x reference)
//
#include <hip/hip_runtime.h>
#include <stdint.h>

// Problem constants
// x: [4, 64, 128, 128, 10] f32, W: [10, 32, 64, 3,3,3] f32
// out: [4, 96, 128, 128, 10] f32 = cat([x, leaky_relu(conv)], axis=1)

typedef __bf16 bf16x8 __attribute__((ext_vector_type(8)));
typedef float f32x4 __attribute__((ext_vector_type(4)));

__device__ __forceinline__ unsigned short f2bf(float f) {
    union { float f; uint32_t u; } v; v.f = f;
    uint32_t u = v.u;
    // round-to-nearest-even (inputs are finite randn; no NaN handling needed)
    uint32_t r = (u + 0x7FFFu + ((u >> 16) & 1u)) >> 16;
    return (unsigned short)r;
}

// Repack weights: W[z,o,c,kd,kh,kw] f32 -> Wt[z][tap][cg][o][ce] bf16
// tap = kd*9+kh*3+kw, c = cg*8+ce. Total 10*27*8*32*8 = 552960 halfs (1.08 MB).
__global__ void prep_weights(const float* __restrict__ w, unsigned short* __restrict__ wt) {
    int t = blockIdx.x * 256 + threadIdx.x;
    if (t >= 552960) return;
    int ce  = t & 7;
    int o   = (t >> 3) & 31;
    int cg  = (t >> 8) & 7;
    int tap = (t >> 11) % 27;
    int z   = t / 55296;
    int c   = cg * 8 + ce;
    float v = w[((z * 32 + o) * 64 + c) * 27 + tap];
    wt[t] = f2bf(v);
}

// out[:, 0:64] = x  (exact f32 copy, vectorized)
__global__ void copy_x(const float4* __restrict__ x, float4* __restrict__ out) {
    const int n = 10485760;                 // 41943040 f32 / 4
    for (int i = blockIdx.x * blockDim.x + threadIdx.x; i < n; i += gridDim.x * blockDim.x) {
        int b = i / 2621440;                // float4 per batch in x
        int rem = i - b * 2621440;
        out[b * 3932160 + rem] = x[i];      // out batch stride = 15728640 f32 / 4
    }
}

#define RS 392   // LDS row stride in halfs: 12*32 + 8 pad (784 B == 16 mod 128 -> low bank conflict)

// Block: (b, d, h-tile of 64). 4 waves: wave = (z-half zh, m-pair mp).
// Wave computes out[b, 64+o(0..31), d, h0 + mp*32 .. +31, z in zh*5..zh*5+4].
__global__ __launch_bounds__(256, 2) void conv_lc3d(
        const float* __restrict__ x, const unsigned short* __restrict__ wt,
        float* __restrict__ out) {
    __shared__ __align__(16) unsigned short xls[66 * RS];

    const int bid = blockIdx.x;
    const int ht = bid & 1;
    const int d  = (bid >> 1) & 127;
    const int b  = bid >> 8;
    const int h0 = ht * 64;

    const int tid = threadIdx.x;
    const int l  = tid & 63;
    const int w  = tid >> 6;
    const int zh = w >> 1;      // z-half: 0 -> z 0..4, 1 -> z 5..9
    const int mp = w & 1;       // m-pair: h-local [mp*32, mp*32+32)
    const int lr = l & 15;      // fragment row/col
    const int lk = l >> 4;      // k-group (8 c each)

    f32x4 acc[2][5][2];
    #pragma unroll
    for (int m = 0; m < 2; ++m)
        #pragma unroll
        for (int zl = 0; zl < 5; ++zl)
            #pragma unroll
            for (int oh = 0; oh < 2; ++oh)
                acc[m][zl][oh] = (f32x4){0.f, 0.f, 0.f, 0.f};

    // zero z-pad planes (zz = 0 and 11) once; staging only writes zz 1..10
    for (int i = tid; i < 66 * 32; i += 256) {
        int hh = i >> 5, cl = i & 31;
        xls[hh * RS + cl] = 0;
        xls[hh * RS + 11 * 32 + cl] = 0;
    }

    const float* xb = x + (size_t)b * 10485760;

    for (int cc = 0; cc < 2; ++cc) {
        for (int kd = 0; kd < 3; ++kd) {
            const int dg = d - 1 + kd;
            const bool dgv = (dg >= 0) && (dg < 128);
            __syncthreads();   // protect LDS from readers of previous slab
            // stage x[b, cc*32..+32, dg, h0-1..h0+64, :] -> xls[hh][zz][cl] (bf16)
            for (int cl = w; cl < 32; cl += 4) {
                const float* src = xb + (size_t)(cc * 32 + cl) * 163840 + (size_t)dg * 1280 + (h0 - 1) * 10;
                for (int j = l; j < 660; j += 64) {
                    int hh = j / 10;
                    int zz = j - hh * 10 + 1;
                    int hg = h0 - 1 + hh;
                    float v = 0.f;
                    if (dgv && hg >= 0 && hg < 128) v = src[j];
                    xls[hh * RS + zz * 32 + cl] = f2bf(v);
                }
            }
            __syncthreads();

            #pragma unroll
            for (int kh = 0; kh < 3; ++kh) {
                #pragma unroll
                for (int u = 0; u < 7; ++u) {
                    const int zp = zh * 5 + u;   // padded-z index into LDS
                    const bf16x8 a0 = *(const bf16x8*)&xls[(mp * 32 + lr + kh) * RS + zp * 32 + lk * 8];
                    const bf16x8 a1 = *(const bf16x8*)&xls[(mp * 32 + 16 + lr + kh) * RS + zp * 32 + lk * 8];
                    #pragma unroll
                    for (int kw = 0; kw < 3; ++kw) {
                        const int zl = u - kw;          // compile-time
                        if (zl < 0 || zl >= 5) continue;
                        const int z = zh * 5 + zl;
                        const int tap = kd * 9 + kh * 3 + kw;
                        #pragma unroll
                        for (int oh = 0; oh < 2; ++oh) {
                            const bf16x8 bf = *(const bf16x8*)&wt[
                                (size_t)(((z * 27 + tap) * 8 + cc * 4 + lk) * 32 + oh * 16 + lr) * 8];
                            acc[0][zl][oh] = __builtin_amdgcn_mfma_f32_16x16x32_bf16(a0, bf, acc[0][zl][oh], 0, 0, 0);
                            acc[1][zl][oh] = __builtin_amdgcn_mfma_f32_16x16x32_bf16(a1, bf, acc[1][zl][oh], 0, 0, 0);
                        }
                    }
                }
            }
        }
    }

    // epilogue: leaky-relu + store. C/D layout: col(o)=lane&15, row(h)=(lane>>4)*4+r
    float* ob = out + (size_t)b * 15728640 + (size_t)d * 1280;
    #pragma unroll
    for (int m = 0; m < 2; ++m) {
        #pragma unroll
        for (int zl = 0; zl < 5; ++zl) {
            #pragma unroll
            for (int oh = 0; oh < 2; ++oh) {
                const int z = zh * 5 + zl;
                const int o = oh * 16 + lr;
                const int hl = (mp * 2 + m) * 16 + lk * 4;
                float* p = ob + (size_t)(64 + o) * 163840 + (h0 + hl) * 10 + z;
                #pragma unroll
                for (int r = 0; r < 4; ++r) {
                    float v = acc[m][zl][oh][r];
                    v = (v >= 0.f) ? v : 0.2f * v;
                    p[r * 10] = v;
                }
            }
        }
    }
}

extern "C" void kernel_launch(void* const* d_in, const int* in_sizes, int n_in,
                              void* d_out, int out_size, void* d_ws, size_t ws_size,
                              hipStream_t stream) {
    const float* x   = (const float*)d_in[0];
    const float* wts = (const float*)d_in[1];
    float* out = (float*)d_out;
    unsigned short* wt = (unsigned short*)d_ws;   // needs 1,105,920 bytes of d_ws

    prep_weights<<<2160, 256, 0, stream>>>(wts, wt);
    copy_x<<<2048, 256, 0, stream>>>((const float4*)x, (float4*)out);
    conv_lc3d<<<4 * 128 * 2, 256, 0, stream>>>(x, wt, out);
}

// Round 2
// 433.043 us; speedup vs baseline: 1.6386x; 1.6386x over previous
//
#include <hip/hip_runtime.h>
#include <stdint.h>

// x: [4, 64, 128, 128, 10] f32, W: [10, 32, 64, 3,3,3] f32
// out: [4, 96, 128, 128, 10] f32 = cat([x, leaky_relu(conv)], axis=1)

typedef __bf16 bf16x8 __attribute__((ext_vector_type(8)));
typedef float f32x4 __attribute__((ext_vector_type(4)));
typedef unsigned short ushort_t;

__device__ __forceinline__ ushort_t f2bf(float f) {
    union { float f; uint32_t u; } v; v.f = f;
    uint32_t u = v.u;
    uint32_t r = (u + 0x7FFFu + ((u >> 16) & 1u)) >> 16;   // RNE
    return (ushort_t)r;
}

// ---------------- weights repack (shared by both paths) ----------------
// W[z,o,c,kd,kh,kw] f32 -> wt[(z*27+tap)*2048 + cg*256 + o*8 + ce] bf16
// (cg = c/8, ce = c%8, tap = kd*9+kh*3+kw). 552,960 halfs = 1.08 MB.
__global__ void prep_weights(const float* __restrict__ w, ushort_t* __restrict__ wt) {
    int t = blockIdx.x * 256 + threadIdx.x;
    if (t >= 552960) return;
    int ce  = t & 7;
    int o   = (t >> 3) & 31;
    int cg  = (t >> 8) & 7;
    int tap = (t >> 11) % 27;
    int z   = t / 55296;
    int c   = cg * 8 + ce;
    wt[t] = f2bf(w[((z * 32 + o) * 64 + c) * 27 + tap]);
}

// ======================= FAST PATH (needs ~104 MB ws) =======================
// xt layout: [b:4][d:128][hp:130][zp:12][c:64] bf16, zeros at hp in {0,129}, zp in {0,11}
#define XT_B  12779520   // 128*130*12*64
#define XT_D  99840      // 130*768
#define XT_H  768        // 12*64

// zero the hp = 0 and hp = 129 planes. grid 1024 (b*256 + d*2 + e), 128 threads.
__global__ void zero_hpads(ushort_t* __restrict__ xt) {
    int tid = threadIdx.x;
    if (tid >= 96) return;
    int bid = blockIdx.x;
    int e = bid & 1, d = (bid >> 1) & 127, b = bid >> 8;
    int hp = e ? 129 : 0;
    size_t u16off = ((size_t)(b * 128 + d) * 130 + hp) * 768;
    uint4 zz = {0u, 0u, 0u, 0u};
    ((uint4*)xt)[u16off / 8 + tid] = zz;
}

// fused: out[:, 0:64] = x  AND  repack x -> xt (bf16, transposed, z-padded).
// grid = 4*128*8 = 4096 blocks (b*1024 + d*8 + hc), 256 threads.
__global__ __launch_bounds__(256) void repack_copy(
        const float* __restrict__ x, float* __restrict__ out, ushort_t* __restrict__ xt) {
    __shared__ __align__(16) ushort_t sm[16 * 12 * 64];   // [hl][zp][c] 24576 B

    int bid = blockIdx.x;
    int hc = bid & 7, d = (bid >> 3) & 127, b = bid >> 10;
    int h0 = hc * 16;
    int tid = threadIdx.x;
    int c = tid >> 2, q0 = tid & 3;

    // zero z-pad slots (zp = 0 and 11): 256 x 16B
    {
        int hl = tid >> 4, rest = tid & 15;
        int zp = (rest >> 3) ? 11 : 0, s = rest & 7;
        uint4 zz = {0u, 0u, 0u, 0u};
        *(uint4*)&sm[hl * 768 + zp * 64 + s * 8] = zz;
    }

    const float4* s4 = (const float4*)(x   + ((size_t)(b * 64 + c) * 128 + d) * 1280 + h0 * 10);
    float4*       d4 = (float4*)      (out + ((size_t)(b * 96 + c) * 128 + d) * 1280 + h0 * 10);

    #pragma unroll
    for (int i = 0; i < 10; ++i) {
        int j = q0 + 4 * i;            // 40 float4 per c-row, 4 threads per row
        float4 v = s4[j];
        d4[j] = v;                      // exact f32 copy of x into out[:, :64]
        int p = 4 * j;                  // 0..636
        int hl = (p * 52429) >> 19;     // p / 10
        int zz = p - 10 * hl;           // 0..9
        int addr = hl * 768 + (zz + 1) * 64 + c;
        float vv[4] = {v.x, v.y, v.z, v.w};
        #pragma unroll
        for (int k = 0; k < 4; ++k) {
            sm[addr] = f2bf(vv[k]);
            zz++;
            if (zz == 10) { zz = 0; addr += 192; } else addr += 64;
        }
    }
    __syncthreads();

    // write xt block: hp = h0+1 .. h0+16, contiguous [16][12][64] u16 = 1536 x 16B
    uint4* dx = (uint4*)(xt + ((size_t)(b * 128 + d) * 130 + h0 + 1) * 768);
    const uint4* sv = (const uint4*)sm;
    #pragma unroll
    for (int i = 0; i < 6; ++i) dx[tid + 256 * i] = sv[tid + 256 * i];
}

// conv: LDS-free, barrier-free implicit GEMM. grid 512 (b,d), 4 waves = (ht, zh).
// wave: 64 h (4 m-tiles) x 32 o (2 oh) x 5 z (its zh half). acc[m][zl][oh] in AGPRs.
__global__ __launch_bounds__(256) void conv_lc3d(
        const ushort_t* __restrict__ xt, const ushort_t* __restrict__ wt,
        float* __restrict__ out) {
    int bid = blockIdx.x;
    int swz = ((bid & 7) << 6) + (bid >> 3);   // XCD-chunked, bijective (512 % 8 == 0)
    int d = swz & 127, b = swz >> 7;
    int tid = threadIdx.x;
    int l = tid & 63, w = tid >> 6;
    int ht = w & 1, zh = w >> 1;
    int lr = l & 15, lk = l >> 4;
    int h0 = ht << 6;

    f32x4 acc[4][5][2];
    #pragma unroll
    for (int m = 0; m < 4; ++m)
        #pragma unroll
        for (int zl = 0; zl < 5; ++zl)
            #pragma unroll
            for (int oh = 0; oh < 2; ++oh)
                acc[m][zl][oh] = (f32x4){0.f, 0.f, 0.f, 0.f};

    const ushort_t* xb = xt + (size_t)b * XT_B;
    const ushort_t* wl = wt + (size_t)lr * 8;     // o-low part of B address

    for (int cc = 0; cc < 2; ++cc) {
        for (int kd = 0; kd < 3; ++kd) {
            int dg = d - 1 + kd;
            if (dg < 0 || dg > 127) continue;     // block-uniform
            const ushort_t* xs = xb + (size_t)dg * XT_D + (size_t)(h0 + lr) * XT_H
                                 + (zh * 5) * 64 + cc * 32 + lk * 8;
            const ushort_t* wb = wl + (size_t)(cc * 4 + lk) * 256;
            for (int kh = 0; kh < 3; ++kh) {
                // preload all 30 B-fragments for this (cc, kd, kh)
                bf16x8 bb[5][3][2];
                #pragma unroll
                for (int zl = 0; zl < 5; ++zl)
                    #pragma unroll
                    for (int kw = 0; kw < 3; ++kw) {
                        int z = zh * 5 + zl;
                        int tap = (kd * 3 + kh) * 3 + kw;
                        size_t off = (size_t)(z * 27 + tap) * 2048;
                        #pragma unroll
                        for (int oh = 0; oh < 2; ++oh)
                            bb[zl][kw][oh] = *(const bf16x8*)&wb[off + oh * 128];
                    }
                const ushort_t* xk = xs + kh * XT_H;
                #pragma unroll
                for (int u = 0; u < 7; ++u) {      // padded zp = zh*5 + u
                    bf16x8 a[4];
                    #pragma unroll
                    for (int m = 0; m < 4; ++m)
                        a[m] = *(const bf16x8*)&xk[m * 16 * XT_H + u * 64];
                    #pragma unroll
                    for (int kw = 0; kw < 3; ++kw) {
                        int zl = u - kw;
                        if (zl < 0 || zl > 4) continue;   // compile-time
                        #pragma unroll
                        for (int oh = 0; oh < 2; ++oh)
                            #pragma unroll
                            for (int m = 0; m < 4; ++m)
                                acc[m][zl][oh] = __builtin_amdgcn_mfma_f32_16x16x32_bf16(
                                    a[m], bb[zl][kw][oh], acc[m][zl][oh], 0, 0, 0);
                    }
                }
            }
        }
    }

    // epilogue: leaky-relu + scalar stores. C/D: col(o)=lane&15, row(h)=lk*4+r
    float* ob = out + (size_t)b * 15728640 + (size_t)64 * 163840 + (size_t)d * 1280 + zh * 5;
    #pragma unroll
    for (int m = 0; m < 4; ++m)
        #pragma unroll
        for (int oh = 0; oh < 2; ++oh) {
            int o = oh * 16 + lr;
            #pragma unroll
            for (int r = 0; r < 4; ++r) {
                int h = h0 + m * 16 + lk * 4 + r;
                float* p = ob + (size_t)o * 163840 + h * 10;
                #pragma unroll
                for (int zl = 0; zl < 5; ++zl) {
                    float v = acc[m][zl][oh][r];
                    p[zl] = (v >= 0.f) ? v : 0.2f * v;
                }
            }
        }
}

// ======================= FALLBACK PATH (R1 kernel, ~1.1 MB ws) =======================
__global__ void copy_x(const float4* __restrict__ x, float4* __restrict__ out) {
    const int n = 10485760;
    for (int i = blockIdx.x * blockDim.x + threadIdx.x; i < n; i += gridDim.x * blockDim.x) {
        int b = i / 2621440;
        int rem = i - b * 2621440;
        out[b * 3932160 + rem] = x[i];
    }
}

#define RS 392
__global__ __launch_bounds__(256, 2) void conv_lc3d_v1(
        const float* __restrict__ x, const ushort_t* __restrict__ wt,
        float* __restrict__ out) {
    __shared__ __align__(16) ushort_t xls[66 * RS];
    const int bid = blockIdx.x;
    const int ht = bid & 1;
    const int d  = (bid >> 1) & 127;
    const int b  = bid >> 8;
    const int h0 = ht * 64;
    const int tid = threadIdx.x;
    const int l  = tid & 63;
    const int w  = tid >> 6;
    const int zh = w >> 1;
    const int mp = w & 1;
    const int lr = l & 15;
    const int lk = l >> 4;

    f32x4 acc[2][5][2];
    #pragma unroll
    for (int m = 0; m < 2; ++m)
        #pragma unroll
        for (int zl = 0; zl < 5; ++zl)
            #pragma unroll
            for (int oh = 0; oh < 2; ++oh)
                acc[m][zl][oh] = (f32x4){0.f, 0.f, 0.f, 0.f};

    for (int i = tid; i < 66 * 32; i += 256) {
        int hh = i >> 5, cl = i & 31;
        xls[hh * RS + cl] = 0;
        xls[hh * RS + 11 * 32 + cl] = 0;
    }
    const float* xb = x + (size_t)b * 10485760;
    for (int cc = 0; cc < 2; ++cc) {
        for (int kd = 0; kd < 3; ++kd) {
            const int dg = d - 1 + kd;
            const bool dgv = (dg >= 0) && (dg < 128);
            __syncthreads();
            for (int cl = w; cl < 32; cl += 4) {
                const float* src = xb + (size_t)(cc * 32 + cl) * 163840 + (size_t)dg * 1280 + (h0 - 1) * 10;
                for (int j = l; j < 660; j += 64) {
                    int hh = j / 10;
                    int zz = j - hh * 10 + 1;
                    int hg = h0 - 1 + hh;
                    float v = 0.f;
                    if (dgv && hg >= 0 && hg < 128) v = src[j];
                    xls[hh * RS + zz * 32 + cl] = f2bf(v);
                }
            }
            __syncthreads();
            #pragma unroll
            for (int kh = 0; kh < 3; ++kh) {
                #pragma unroll
                for (int u = 0; u < 7; ++u) {
                    const int zp = zh * 5 + u;
                    const bf16x8 a0 = *(const bf16x8*)&xls[(mp * 32 + lr + kh) * RS + zp * 32 + lk * 8];
                    const bf16x8 a1 = *(const bf16x8*)&xls[(mp * 32 + 16 + lr + kh) * RS + zp * 32 + lk * 8];
                    #pragma unroll
                    for (int kw = 0; kw < 3; ++kw) {
                        const int zl = u - kw;
                        if (zl < 0 || zl >= 5) continue;
                        const int z = zh * 5 + zl;
                        const int tap = kd * 9 + kh * 3 + kw;
                        #pragma unroll
                        for (int oh = 0; oh < 2; ++oh) {
                            const bf16x8 bf = *(const bf16x8*)&wt[
                                (size_t)(((z * 27 + tap) * 8 + cc * 4 + lk) * 32 + oh * 16 + lr) * 8];
                            acc[0][zl][oh] = __builtin_amdgcn_mfma_f32_16x16x32_bf16(a0, bf, acc[0][zl][oh], 0, 0, 0);
                            acc[1][zl][oh] = __builtin_amdgcn_mfma_f32_16x16x32_bf16(a1, bf, acc[1][zl][oh], 0, 0, 0);
                        }
                    }
                }
            }
        }
    }
    float* ob = out + (size_t)b * 15728640 + (size_t)d * 1280;
    #pragma unroll
    for (int m = 0; m < 2; ++m)
        #pragma unroll
        for (int zl = 0; zl < 5; ++zl)
            #pragma unroll
            for (int oh = 0; oh < 2; ++oh) {
                const int z = zh * 5 + zl;
                const int o = oh * 16 + lr;
                const int hl = (mp * 2 + m) * 16 + lk * 4;
                float* p = ob + (size_t)(64 + o) * 163840 + (h0 + hl) * 10 + z;
                #pragma unroll
                for (int r = 0; r < 4; ++r) {
                    float v = acc[m][zl][oh][r];
                    v = (v >= 0.f) ? v : 0.2f * v;
                    p[r * 10] = v;
                }
            }
}

// =============================== launch ===============================
extern "C" void kernel_launch(void* const* d_in, const int* in_sizes, int n_in,
                              void* d_out, int out_size, void* d_ws, size_t ws_size,
                              hipStream_t stream) {
    const float* x   = (const float*)d_in[0];
    const float* wts = (const float*)d_in[1];
    float* out = (float*)d_out;
    ushort_t* wt = (ushort_t*)d_ws;

    const size_t XT_OFF = 2u << 20;                       // 2 MiB (wt needs 1.08 MiB)
    const size_t NEED = XT_OFF + (size_t)4 * XT_B * 2;    // + 102.2 MB xt

    prep_weights<<<2160, 256, 0, stream>>>(wts, wt);

    if (ws_size >= NEED) {
        ushort_t* xtp = (ushort_t*)((char*)d_ws + XT_OFF);
        zero_hpads<<<1024, 128, 0, stream>>>(xtp);
        repack_copy<<<4096, 256, 0, stream>>>(x, out, xtp);
        conv_lc3d<<<512, 256, 0, stream>>>(xtp, wt, out);
    } else {
        copy_x<<<2048, 256, 0, stream>>>((const float4*)x, (float4*)out);
        conv_lc3d_v1<<<4 * 128 * 2, 256, 0, stream>>>(x, wt, out);
    }
}

// Round 3
// 375.759 us; speedup vs baseline: 1.8884x; 1.1524x over previous
//
#include <hip/hip_runtime.h>
#include <stdint.h>

// x: [4, 64, 128, 128, 10] f32, W: [10, 32, 64, 3,3,3] f32
// out: [4, 96, 128, 128, 10] f32 = cat([x, leaky_relu(conv)], axis=1)

typedef __bf16 bf16x8 __attribute__((ext_vector_type(8)));
typedef float f32x4 __attribute__((ext_vector_type(4)));
typedef unsigned short ushort_t;

__device__ __forceinline__ ushort_t f2bf(float f) {
    union { float f; uint32_t u; } v; v.f = f;
    uint32_t u = v.u;
    uint32_t r = (u + 0x7FFFu + ((u >> 16) & 1u)) >> 16;   // RNE
    return (ushort_t)r;
}

// ---------------- weights repack ----------------
// W[z,o,c,kd,kh,kw] f32 -> wt[(z*27+tap)*2048 + cg*256 + o*8 + ce] bf16
__global__ void prep_weights(const float* __restrict__ w, ushort_t* __restrict__ wt) {
    int t = blockIdx.x * 256 + threadIdx.x;
    if (t >= 552960) return;
    int ce  = t & 7;
    int o   = (t >> 3) & 31;
    int cg  = (t >> 8) & 7;
    int tap = (t >> 11) % 27;
    int z   = t / 55296;
    int c   = cg * 8 + ce;
    wt[t] = f2bf(w[((z * 32 + o) * 64 + c) * 27 + tap]);
}

// ======================= FAST PATH =======================
// xt layout: [b:4][d:128][hp:130][zp:12][c:64] bf16, zeros at hp in {0,129}, zp in {0,11}
#define XT_B  12779520   // 128*130*12*64
#define XT_D  99840      // 130*768
#define XT_H  768        // 12*64

__global__ void zero_hpads(ushort_t* __restrict__ xt) {
    int tid = threadIdx.x;
    if (tid >= 96) return;
    int bid = blockIdx.x;
    int e = bid & 1, d = (bid >> 1) & 127, b = bid >> 8;
    int hp = e ? 129 : 0;
    size_t u16off = ((size_t)(b * 128 + d) * 130 + hp) * 768;
    uint4 zz = {0u, 0u, 0u, 0u};
    ((uint4*)xt)[u16off / 8 + tid] = zz;
}

// fused: out[:, 0:64] = x  AND  repack x -> xt (bf16, transposed, z-padded).
__global__ __launch_bounds__(256) void repack_copy(
        const float* __restrict__ x, float* __restrict__ out, ushort_t* __restrict__ xt) {
    __shared__ __align__(16) ushort_t sm[16 * 12 * 64];

    int bid = blockIdx.x;
    int hc = bid & 7, d = (bid >> 3) & 127, b = bid >> 10;
    int h0 = hc * 16;
    int tid = threadIdx.x;
    int c = tid >> 2, q0 = tid & 3;

    {
        int hl = tid >> 4, rest = tid & 15;
        int zp = (rest >> 3) ? 11 : 0, s = rest & 7;
        uint4 zz = {0u, 0u, 0u, 0u};
        *(uint4*)&sm[hl * 768 + zp * 64 + s * 8] = zz;
    }

    const float4* s4 = (const float4*)(x   + ((size_t)(b * 64 + c) * 128 + d) * 1280 + h0 * 10);
    float4*       d4 = (float4*)      (out + ((size_t)(b * 96 + c) * 128 + d) * 1280 + h0 * 10);

    #pragma unroll
    for (int i = 0; i < 10; ++i) {
        int j = q0 + 4 * i;
        float4 v = s4[j];
        d4[j] = v;
        int p = 4 * j;
        int hl = (p * 52429) >> 19;
        int zz = p - 10 * hl;
        int addr = hl * 768 + (zz + 1) * 64 + c;
        float vv[4] = {v.x, v.y, v.z, v.w};
        #pragma unroll
        for (int k = 0; k < 4; ++k) {
            sm[addr] = f2bf(vv[k]);
            zz++;
            if (zz == 10) { zz = 0; addr += 192; } else addr += 64;
        }
    }
    __syncthreads();

    uint4* dx = (uint4*)(xt + ((size_t)(b * 128 + d) * 130 + h0 + 1) * 768);
    const uint4* sv = (const uint4*)sm;
    #pragma unroll
    for (int i = 0; i < 6; ++i) dx[tid + 256 * i] = sv[tid + 256 * i];
}

// conv v3: LDS-staged A (global_load_lds w16, rotation-swizzled), B from L2.
// grid 1024 = (b, d, ht). 128 threads = 2 waves (zh). Wave: 64h x 32o x 5z.
typedef __attribute__((address_space(3))) uint32_t lds_w;
typedef const __attribute__((address_space(1))) uint32_t glb_w;

__global__ __launch_bounds__(128) void conv_v3(
        const ushort_t* __restrict__ xt, const ushort_t* __restrict__ wt,
        float* __restrict__ out) {
    __shared__ __align__(16) uint4 SL[3264];   // 67 rows x 48 granules (+pad) = 51 KB

    int bid = blockIdx.x;
    int swz = ((bid & 7) << 7) | (bid >> 3);   // XCD-chunked, bijective (1024 % 8 == 0)
    int ht = swz & 1, d = (swz >> 1) & 127, b = swz >> 8;
    int h0 = ht << 6;

    int tid = threadIdx.x;
    int l = tid & 63, w = tid >> 6;
    int zh = w;                 // wave id = z-half
    int lr = l & 15, lk = l >> 4;

    f32x4 acc[4][5][2];
    #pragma unroll
    for (int m = 0; m < 4; ++m)
        #pragma unroll
        for (int zl = 0; zl < 5; ++zl)
            #pragma unroll
            for (int oh = 0; oh < 2; ++oh)
                acc[m][zl][oh] = (f32x4){0.f, 0.f, 0.f, 0.f};

    const ushort_t* xb = xt + (size_t)b * XT_B;
    const ushort_t* wl = wt + (size_t)lr * 8;

    for (int cc = 0; cc < 2; ++cc) {
        const ushort_t* wb = wl + (size_t)(cc * 4 + lk) * 256;
        for (int kd = 0; kd < 3; ++kd) {
            int dg = d - 1 + kd;
            if (dg < 0 || dg > 127) continue;       // block-uniform

            __syncthreads();    // previous slab fully consumed
            // ---- stage slab [row 0..65][g' 0..47] via global_load_lds (16B) ----
            // LDS[row][g'] <- xt granule g = (g' - 5*(row&7)) mod 48 of padded-h row (h0+row)
            const ushort_t* sb = xb + (size_t)dg * XT_D + cc * 32;
            #pragma unroll
            for (int i = 0; i < 25; ++i) {
                int s = i * 128 + tid;
                int row = (int)(((unsigned)s * 43691u) >> 21);    // s / 48
                int gp = s - row * 48;
                int g = gp - 5 * (row & 7);
                if (g < 0) g += 48;
                int hp = h0 + row;
                if (hp > 129) hp = 129;                            // garbage rows, never read
                int zp = g >> 2, q = g & 3;
                const ushort_t* src = sb + (size_t)hp * 768 + zp * 64 + q * 8;
                uint4* dst = SL + (i * 128 + w * 64);              // wave-uniform base
                __builtin_amdgcn_global_load_lds((glb_w*)src, (lds_w*)dst, 16, 0, 0);
            }
            asm volatile("s_waitcnt vmcnt(0)" ::: "memory");
            __syncthreads();

            // ---- compute ----
            #pragma unroll
            for (int kh = 0; kh < 3; ++kh) {
                bf16x8 bb[5][3][2];
                #pragma unroll
                for (int zl = 0; zl < 5; ++zl)
                    #pragma unroll
                    for (int kw = 0; kw < 3; ++kw) {
                        int z = zh * 5 + zl;
                        int tap = (kd * 3 + kh) * 3 + kw;
                        size_t off = (size_t)(z * 27 + tap) * 2048;
                        #pragma unroll
                        for (int oh = 0; oh < 2; ++oh)
                            bb[zl][kw][oh] = *(const bf16x8*)&wb[off + oh * 128];
                    }
                const int rot = 5 * ((lr + kh) & 7);
                const int rowb = lr + kh;
                #pragma unroll
                for (int u = 0; u < 7; ++u) {
                    int g0 = 20 * zh + 4 * u + lk + rot;
                    int gp = (g0 >= 48) ? g0 - 48 : g0;
                    bf16x8 a[4];
                    #pragma unroll
                    for (int m = 0; m < 4; ++m)
                        a[m] = *(const bf16x8*)((const ushort_t*)SL
                                + (size_t)(m * 16 + rowb) * 384 + gp * 8);
                    #pragma unroll
                    for (int kw = 0; kw < 3; ++kw) {
                        int zl = u - kw;
                        if (zl < 0 || zl > 4) continue;            // compile-time
                        #pragma unroll
                        for (int oh = 0; oh < 2; ++oh)
                            #pragma unroll
                            for (int m = 0; m < 4; ++m)
                                acc[m][zl][oh] = __builtin_amdgcn_mfma_f32_16x16x32_bf16(
                                    a[m], bb[zl][kw][oh], acc[m][zl][oh], 0, 0, 0);
                    }
                }
            }
        }
    }

    // epilogue: leaky-relu + store. C/D: col(o)=lane&15, row(h-in-tile)=lk*4+r
    float* ob = out + (size_t)b * 15728640 + (size_t)64 * 163840 + (size_t)d * 1280 + zh * 5;
    #pragma unroll
    for (int m = 0; m < 4; ++m)
        #pragma unroll
        for (int oh = 0; oh < 2; ++oh) {
            int o = oh * 16 + lr;
            #pragma unroll
            for (int r = 0; r < 4; ++r) {
                int h = h0 + m * 16 + lk * 4 + r;
                float* p = ob + (size_t)o * 163840 + h * 10;
                #pragma unroll
                for (int zl = 0; zl < 5; ++zl) {
                    float v = acc[m][zl][oh][r];
                    p[zl] = (v >= 0.f) ? v : 0.2f * v;
                }
            }
        }
}

// ======================= FALLBACK PATH (R1) =======================
__global__ void copy_x(const float4* __restrict__ x, float4* __restrict__ out) {
    const int n = 10485760;
    for (int i = blockIdx.x * blockDim.x + threadIdx.x; i < n; i += gridDim.x * blockDim.x) {
        int b = i / 2621440;
        int rem = i - b * 2621440;
        out[b * 3932160 + rem] = x[i];
    }
}

#define RS 392
__global__ __launch_bounds__(256, 2) void conv_lc3d_v1(
        const float* __restrict__ x, const ushort_t* __restrict__ wt,
        float* __restrict__ out) {
    __shared__ __align__(16) ushort_t xls[66 * RS];
    const int bid = blockIdx.x;
    const int ht = bid & 1;
    const int d  = (bid >> 1) & 127;
    const int b  = bid >> 8;
    const int h0 = ht * 64;
    const int tid = threadIdx.x;
    const int l  = tid & 63;
    const int w  = tid >> 6;
    const int zh = w >> 1;
    const int mp = w & 1;
    const int lr = l & 15;
    const int lk = l >> 4;

    f32x4 acc[2][5][2];
    #pragma unroll
    for (int m = 0; m < 2; ++m)
        #pragma unroll
        for (int zl = 0; zl < 5; ++zl)
            #pragma unroll
            for (int oh = 0; oh < 2; ++oh)
                acc[m][zl][oh] = (f32x4){0.f, 0.f, 0.f, 0.f};

    for (int i = tid; i < 66 * 32; i += 256) {
        int hh = i >> 5, cl = i & 31;
        xls[hh * RS + cl] = 0;
        xls[hh * RS + 11 * 32 + cl] = 0;
    }
    const float* xb = x + (size_t)b * 10485760;
    for (int cc = 0; cc < 2; ++cc) {
        for (int kd = 0; kd < 3; ++kd) {
            const int dg = d - 1 + kd;
            const bool dgv = (dg >= 0) && (dg < 128);
            __syncthreads();
            for (int cl = w; cl < 32; cl += 4) {
                const float* src = xb + (size_t)(cc * 32 + cl) * 163840 + (size_t)dg * 1280 + (h0 - 1) * 10;
                for (int j = l; j < 660; j += 64) {
                    int hh = j / 10;
                    int zz = j - hh * 10 + 1;
                    int hg = h0 - 1 + hh;
                    float v = 0.f;
                    if (dgv && hg >= 0 && hg < 128) v = src[j];
                    xls[hh * RS + zz * 32 + cl] = f2bf(v);
                }
            }
            __syncthreads();
            #pragma unroll
            for (int kh = 0; kh < 3; ++kh) {
                #pragma unroll
                for (int u = 0; u < 7; ++u) {
                    const int zp = zh * 5 + u;
                    const bf16x8 a0 = *(const bf16x8*)&xls[(mp * 32 + lr + kh) * RS + zp * 32 + lk * 8];
                    const bf16x8 a1 = *(const bf16x8*)&xls[(mp * 32 + 16 + lr + kh) * RS + zp * 32 + lk * 8];
                    #pragma unroll
                    for (int kw = 0; kw < 3; ++kw) {
                        const int zl = u - kw;
                        if (zl < 0 || zl >= 5) continue;
                        const int z = zh * 5 + zl;
                        const int tap = kd * 9 + kh * 3 + kw;
                        #pragma unroll
                        for (int oh = 0; oh < 2; ++oh) {
                            const bf16x8 bf = *(const bf16x8*)&wt[
                                (size_t)(((z * 27 + tap) * 8 + cc * 4 + lk) * 32 + oh * 16 + lr) * 8];
                            acc[0][zl][oh] = __builtin_amdgcn_mfma_f32_16x16x32_bf16(a0, bf, acc[0][zl][oh], 0, 0, 0);
                            acc[1][zl][oh] = __builtin_amdgcn_mfma_f32_16x16x32_bf16(a1, bf, acc[1][zl][oh], 0, 0, 0);
                        }
                    }
                }
            }
        }
    }
    float* ob = out + (size_t)b * 15728640 + (size_t)d * 1280;
    #pragma unroll
    for (int m = 0; m < 2; ++m)
        #pragma unroll
        for (int zl = 0; zl < 5; ++zl)
            #pragma unroll
            for (int oh = 0; oh < 2; ++oh) {
                const int z = zh * 5 + zl;
                const int o = oh * 16 + lr;
                const int hl = (mp * 2 + m) * 16 + lk * 4;
                float* p = ob + (size_t)(64 + o) * 163840 + (h0 + hl) * 10 + z;
                #pragma unroll
                for (int r = 0; r < 4; ++r) {
                    float v = acc[m][zl][oh][r];
                    v = (v >= 0.f) ? v : 0.2f * v;
                    p[r * 10] = v;
                }
            }
}

// =============================== launch ===============================
extern "C" void kernel_launch(void* const* d_in, const int* in_sizes, int n_in,
                              void* d_out, int out_size, void* d_ws, size_t ws_size,
                              hipStream_t stream) {
    const float* x   = (const float*)d_in[0];
    const float* wts = (const float*)d_in[1];
    float* out = (float*)d_out;
    ushort_t* wt = (ushort_t*)d_ws;

    const size_t XT_OFF = 2u << 20;
    const size_t NEED = XT_OFF + (size_t)4 * XT_B * 2;

    prep_weights<<<2160, 256, 0, stream>>>(wts, wt);

    if (ws_size >= NEED) {
        ushort_t* xtp = (ushort_t*)((char*)d_ws + XT_OFF);
        zero_hpads<<<1024, 128, 0, stream>>>(xtp);
        repack_copy<<<4096, 256, 0, stream>>>(x, out, xtp);
        conv_v3<<<1024, 128, 0, stream>>>(xtp, wt, out);
    } else {
        copy_x<<<2048, 256, 0, stream>>>((const float4*)x, (float4*)out);
        conv_lc3d_v1<<<4 * 128 * 2, 256, 0, stream>>>(x, wt, out);
    }
}